// Round 11
// baseline (1427.901 us; speedup 1.0000x reference)
//
#include <hip/hip_runtime.h>
#include <math.h>

#define DD 64
#define TILE 128     // dest nodes per k_agg block (LDS acc = 32 KB)
#define NSLICE 8     // dest-space slices; slice == blockIdx&7 -> one XCD each
#define NCHUNK 128   // edge-list chunks per slice pass
static constexpr float GAMMA_C = 0.1f;
static constexpr float EPS_C = 0.1f;

__device__ __forceinline__ float bf16u(unsigned short h) {
  return __uint_as_float((unsigned int)h << 16);
}

// ---------------------------------------------------------------------------
// Prep: transposed weight copies.
//   aWT[k*64+j] = W[j][k] - W[k][j] - GAMMA*(j==k);  phiWT[k*64+j] = phiW[j][k]
// ---------------------------------------------------------------------------
__global__ __launch_bounds__(256) void k_prep(const float* __restrict__ W1,
                                              const float* __restrict__ phiW1,
                                              const float* __restrict__ W2,
                                              const float* __restrict__ phiW2,
                                              float* __restrict__ aWT1,
                                              float* __restrict__ phiWT1,
                                              float* __restrict__ aWT2,
                                              float* __restrict__ phiWT2) {
  int idx = blockIdx.x * 256 + threadIdx.x;
  if (idx >= 4096) return;
  int k = idx >> 6, j = idx & 63;
  float g = (j == k) ? GAMMA_C : 0.f;
  aWT1[idx] = W1[j * 64 + k] - W1[k * 64 + j] - g;
  aWT2[idx] = W2[j * 64 + k] - W2[k * 64 + j] - g;
  phiWT1[idx] = phiW1[j * 64 + k];
  phiWT2[idx] = phiW2[j * 64 + k];
}

// ---------------------------------------------------------------------------
// Sliced in-degree histogram (atomics stay XCD-local via blockIdx&7 slice).
// ---------------------------------------------------------------------------
__global__ __launch_bounds__(256) void k_hist(const int* __restrict__ col,
                                              int* __restrict__ hist, int e, int n) {
  int slice = blockIdx.x & (NSLICE - 1);
  int chunk = blockIdx.x >> 3;
  int lo = (int)((long long)n * slice / NSLICE);
  int hi = (int)((long long)n * (slice + 1) / NSLICE);
  int per = (e + NCHUNK - 1) / NCHUNK;
  int s = chunk * per;
  int t = min(e, s + per);
  for (int i = s + threadIdx.x; i < t; i += 256) {
    int c = col[i];
    if (c >= lo && c < hi) atomicAdd(&hist[c], 1);
  }
}

__global__ __launch_bounds__(256) void k_scan1(const int* __restrict__ hist,
                                               int* __restrict__ rs,
                                               int* __restrict__ bsum, int n) {
  __shared__ int wtot[4];
  int b = blockIdx.x, t = threadIdx.x;
  int base = b * 2048 + t * 8;
  int v[8];
  int s = 0;
#pragma unroll
  for (int u = 0; u < 8; ++u) {
    int idx = base + u;
    v[u] = (idx < n) ? hist[idx] : 0;
    s += v[u];
  }
  int lane = t & 63, wid = t >> 6;
  int ws = s;
#pragma unroll
  for (int d = 1; d < 64; d <<= 1) {
    int o = __shfl_up(ws, d);
    if (lane >= d) ws += o;
  }
  if (lane == 63) wtot[wid] = ws;
  __syncthreads();
  int off = 0;
  for (int w = 0; w < wid; ++w) off += wtot[w];
  int run = ws - s + off;
#pragma unroll
  for (int u = 0; u < 8; ++u) {
    int idx = base + u;
    if (idx < n) rs[idx] = run;
    run += v[u];
  }
  if (t == 255) bsum[b] = run;
}

__global__ void k_scan2(const int* __restrict__ bsum, int* __restrict__ boff,
                        int nb, int* __restrict__ rs, int n, int e) {
  int t = threadIdx.x;  // single wave; nb <= 64
  int v = (t < nb) ? bsum[t] : 0;
  int s = v;
#pragma unroll
  for (int d = 1; d < 64; d <<= 1) {
    int o = __shfl_up(s, d);
    if (t >= d) s += o;
  }
  if (t < nb) boff[t] = s - v;
  if (t == 0) rs[n] = e;
}

__global__ __launch_bounds__(256) void k_scan3_dinv(int* __restrict__ rs,
                                                    const int* __restrict__ boff,
                                                    const int* __restrict__ hist,
                                                    float* __restrict__ dinv, int n) {
  int i = blockIdx.x * blockDim.x + threadIdx.x;
  if (i < n) {
    rs[i] += boff[i >> 11];
    dinv[i] = rsqrtf((float)(hist[i] + 1));  // +1 self-loop
  }
}

// ---------------------------------------------------------------------------
// Sliced CSR fill; entry packs (dest % TILE)<<24 | src  (src < 2^24).
// ---------------------------------------------------------------------------
__global__ __launch_bounds__(256) void k_fill(const int* __restrict__ row,
                                              const int* __restrict__ col,
                                              const int* __restrict__ rs,
                                              int* __restrict__ fillc,
                                              unsigned int* __restrict__ csr,
                                              int e, int n) {
  int slice = blockIdx.x & (NSLICE - 1);
  int chunk = blockIdx.x >> 3;
  int lo = (int)((long long)n * slice / NSLICE);
  int hi = (int)((long long)n * (slice + 1) / NSLICE);
  int per = (e + NCHUNK - 1) / NCHUNK;
  int s = chunk * per;
  int t = min(e, s + per);
  for (int i = s + threadIdx.x; i < t; i += 256) {
    int c = col[i];
    if (c >= lo && c < hi) {
      int p = atomicAdd(&fillc[c], 1);
      csr[rs[c] + p] = ((unsigned int)(c & (TILE - 1)) << 24) | (unsigned int)row[i];
    }
  }
}

// ---------------------------------------------------------------------------
// xw = bf16( dinv * (x @ phiW^T) ).  Wave-per-QUAD, lane = out feature.
// Weights held in VGPRs (w[64]); x rows via wave-uniform s_loads.
// ---------------------------------------------------------------------------
__global__ __launch_bounds__(256, 4) void k_xw(const float* __restrict__ x,
                                               const float* __restrict__ phiWT,
                                               const float* __restrict__ dinv,
                                               unsigned short* __restrict__ xwh,
                                               int n) {
  int lane = threadIdx.x & 63;
  int gw = __builtin_amdgcn_readfirstlane(
      (int)((blockIdx.x * blockDim.x + threadIdx.x) >> 6));
  int nw = (gridDim.x * blockDim.x) >> 6;
  float w[64];
#pragma unroll
  for (int k = 0; k < 64; ++k) w[k] = phiWT[k * 64 + lane];
  for (int i = 4 * gw; i < n; i += 4 * nw) {
    int j1 = min(i + 1, n - 1), j2 = min(i + 2, n - 1), j3 = min(i + 3, n - 1);
    const float* xr0 = x + (size_t)i * DD;  // uniform -> s_load
    const float* xr1 = x + (size_t)j1 * DD;
    const float* xr2 = x + (size_t)j2 * DD;
    const float* xr3 = x + (size_t)j3 * DD;
    float l0 = 0.f, l1 = 0.f, l2 = 0.f, l3 = 0.f;
#pragma unroll
    for (int kk = 0; kk < 64; ++kk) {
      l0 = fmaf(xr0[kk], w[kk], l0);
      l1 = fmaf(xr1[kk], w[kk], l1);
      l2 = fmaf(xr2[kk], w[kk], l2);
      l3 = fmaf(xr3[kk], w[kk], l3);
    }
    float r0 = dinv[i] * l0, r1 = dinv[j1] * l1;
    float r2 = dinv[j2] * l2, r3 = dinv[j3] * l3;
    auto pack = [](float r) {
      unsigned int u = __float_as_uint(r);
      return (unsigned short)((u + 0x7FFFu + ((u >> 16) & 1u)) >> 16);  // RNE
    };
    size_t o = (size_t)i * DD + lane;
    xwh[o] = pack(r0);
    if (i + 1 < n) xwh[o + DD] = pack(r1);
    if (i + 2 < n) xwh[o + 2 * DD] = pack(r2);
    if (i + 3 < n) xwh[o + 3 * DD] = pack(r3);
  }
}

// ---------------------------------------------------------------------------
// Push-model aggregation. Block owns TILE dest nodes; their in-edges are
// contiguous in csr. Per edge: uniform packed csr read + coalesced 128B bf16
// gather + ds_add_f32 into LDS accumulator (fire-and-forget: no dependent
// chains, ~3 VALU/edge). Epilogue: antisym GEMV from VGPR-resident weights
// + combine (+ output GEMV when FINAL).
// ---------------------------------------------------------------------------
template <bool FINAL>
__global__ __launch_bounds__(256, 3) void k_agg(const float* __restrict__ xin,
                                                const unsigned short* __restrict__ xwh,
                                                const float* __restrict__ aWT,
                                                const float* __restrict__ b,
                                                const unsigned int* __restrict__ csr,
                                                const int* __restrict__ rs,
                                                const float* __restrict__ dinv,
                                                const float* __restrict__ outW,
                                                const float* __restrict__ outb,
                                                float* __restrict__ xo,
                                                float* __restrict__ out, int n) {
  __shared__ float lacc[TILE * DD];  // 32 KB
  int tid = threadIdx.x;
  int lane = tid & 63;
  int wv = tid >> 6;
  int tLo = blockIdx.x * TILE;
  int tHi = min(tLo + TILE, n);
  // VGPR-resident antisym weights (column `lane` of aW^T layout)
  float w[64];
#pragma unroll
  for (int k = 0; k < 64; ++k) w[k] = aWT[k * 64 + lane];
  float bj = b[lane];
  float ow = FINAL ? outW[lane] : 0.f;
  // zero the accumulator tile
  for (int u = tid; u < TILE * DD; u += 256) lacc[u] = 0.f;
  __syncthreads();
  // edge phase: this block's contiguous csr range, split 4 ways by wave
  int eLo = rs[tLo];
  int eHi = rs[tHi];
  int cnt = eHi - eLo;
  int per = (cnt + 3) >> 2;
  int kLo = eLo + wv * per;
  int kHi = min(eHi, kLo + per);
  int k = kLo;
  for (; k + 8 <= kHi; k += 8) {
    unsigned int p[8];
#pragma unroll
    for (int u = 0; u < 8; ++u) p[u] = csr[k + u];  // uniform -> s_load
    float v[8];
#pragma unroll
    for (int u = 0; u < 8; ++u)
      v[u] = bf16u(xwh[(size_t)(p[u] & 0xFFFFFFu) * DD + lane]);
#pragma unroll
    for (int u = 0; u < 8; ++u)
      atomicAdd(&lacc[(p[u] >> 24) * DD + lane], v[u]);
  }
  for (; k < kHi; ++k) {
    unsigned int p = csr[k];
    float v = bf16u(xwh[(size_t)(p & 0xFFFFFFu) * DD + lane]);
    atomicAdd(&lacc[(p >> 24) * DD + lane], v);
  }
  __syncthreads();
  // epilogue: 32 nodes per wave
  int dlEnd = tHi - tLo;
  int dlStop = min(wv * 32 + 32, dlEnd);
  for (int dl = wv * 32; dl < dlStop; ++dl) {
    int i = tLo + dl;
    size_t o = (size_t)i * DD + lane;
    float aggr = dinv[i] * (lacc[dl * DD + lane] + bf16u(xwh[o]));
    const float* xr = xin + (size_t)i * DD;  // uniform -> s_load
    float l0 = 0.f, l1 = 0.f, l2 = 0.f, l3 = 0.f;
#pragma unroll
    for (int kk = 0; kk < 64; kk += 4) {
      l0 = fmaf(xr[kk + 0], w[kk + 0], l0);
      l1 = fmaf(xr[kk + 1], w[kk + 1], l1);
      l2 = fmaf(xr[kk + 2], w[kk + 2], l2);
      l3 = fmaf(xr[kk + 3], w[kk + 3], l3);
    }
    float tot = ((l0 + l1) + (l2 + l3)) + bj + aggr;
    float val = fmaxf(fmaf(EPS_C, tanhf(tot), xin[o]), 0.f);
    if (FINAL) {
      float p = val * ow;
#pragma unroll
      for (int sg = 32; sg > 0; sg >>= 1) p += __shfl_xor(p, sg);
      if (lane == 0) out[i] = p + outb[0];
    } else {
      xo[o] = val;
    }
  }
}

extern "C" void kernel_launch(void* const* d_in, const int* in_sizes, int n_in,
                              void* d_out, int out_size, void* d_ws, size_t ws_size,
                              hipStream_t stream) {
  const float* x     = (const float*)d_in[0];
  const float* W1    = (const float*)d_in[1];
  const float* phiW1 = (const float*)d_in[2];
  const float* b1    = (const float*)d_in[3];
  const float* W2    = (const float*)d_in[4];
  const float* phiW2 = (const float*)d_in[5];
  const float* b2    = (const float*)d_in[6];
  const float* outW  = (const float*)d_in[7];
  const float* outb  = (const float*)d_in[8];
  const int*   ei    = (const int*)d_in[9];

  int n = in_sizes[0] / DD;
  int e = in_sizes[9] / 2;
  const int* row = ei;
  const int* col = ei + e;
  float* out = (float*)d_out;

  // workspace carve (256B-aligned)
  char* w = (char*)d_ws;
  auto carve = [&](size_t bytes) {
    char* p = w;
    w += (bytes + 255) & ~(size_t)255;
    return p;
  };
  float* aWT1   = (float*)carve(4096 * 4);
  float* phiWT1 = (float*)carve(4096 * 4);
  float* aWT2   = (float*)carve(4096 * 4);
  float* phiWT2 = (float*)carve(4096 * 4);
  int*   hist   = (int*)carve((size_t)n * 4);   // hist+fillc adjacent:
  int*   fillc  = (int*)carve((size_t)n * 4);   //   one memset covers both
  int*   rs     = (int*)carve(((size_t)n + 1) * 4);
  int*   bsum   = (int*)carve(64 * 4);
  int*   boff   = (int*)carve(64 * 4);
  float* dinv   = (float*)carve((size_t)n * 4);
  unsigned int* csr = (unsigned int*)carve((size_t)e * 4);
  unsigned short* xwh = (unsigned short*)carve((size_t)n * DD * 2);
  float* x1     = (float*)carve((size_t)n * DD * 4);

  int nb_n   = (n + 255) / 256;
  int nb_sl  = NSLICE * NCHUNK;    // sliced edge kernels (1024 blocks)
  int nb_sc1 = (n + 2047) / 2048;  // scan blocks (49 for n=100k, <=64)
  int nb_xw  = 1024;               // 4096 waves x 4 nodes
  int nb_ag  = (n + TILE - 1) / TILE;  // one block per dest tile (782)

  size_t zbytes = (size_t)((char*)fillc - (char*)hist) + (size_t)n * 4;
  hipMemsetAsync(hist, 0, zbytes, stream);  // zeros hist and fillc

  // prep: transposed antisym/phi weights + CSR + dinv
  k_prep<<<16, 256, 0, stream>>>(W1, phiW1, W2, phiW2, aWT1, phiWT1, aWT2, phiWT2);
  k_hist<<<nb_sl, 256, 0, stream>>>(col, hist, e, n);
  k_scan1<<<nb_sc1, 256, 0, stream>>>(hist, rs, bsum, n);
  k_scan2<<<1, 64, 0, stream>>>(bsum, boff, nb_sc1, rs, n, e);
  k_scan3_dinv<<<nb_n, 256, 0, stream>>>(rs, boff, hist, dinv, n);
  k_fill<<<nb_sl, 256, 0, stream>>>(row, col, rs, fillc, csr, e, n);

  // layer 1
  k_xw<<<nb_xw, 256, 0, stream>>>(x, phiWT1, dinv, xwh, n);
  k_agg<false><<<nb_ag, 256, 0, stream>>>(x, xwh, aWT1, b1, csr, rs, dinv,
                                          nullptr, nullptr, x1, nullptr, n);

  // layer 2 (combine fused with output GEMV)
  k_xw<<<nb_xw, 256, 0, stream>>>(x1, phiWT2, dinv, xwh, n);
  k_agg<true><<<nb_ag, 256, 0, stream>>>(x1, xwh, aWT2, b2, csr, rs, dinv,
                                         outW, outb, nullptr, out, n);
}